// Round 21
// baseline (482.720 us; speedup 1.0000x reference)
//
#include <hip/hip_runtime.h>
#include <hip/hip_bf16.h>
#include <math.h>

#define B 16
#define N 512
#define L 512
#define DIM 10
#define DM 128
#define H 8
#define DK 16
#define DFF 512
#define LG 3
#define LO 3
#define NEGV -9.0e15f
#define RF 16      // rows per block (ffn/qkv/oproj)
#define AQR2 128   // q-rows per attn block (2-slice)
#define KSEG 128   // keys per attn segment
#define NSEG (L / KSEG)
#define RLOG2E 1.44269504f

__device__ __forceinline__ float wave_reduce_sum(float v) {
    #pragma unroll
    for (int o = 32; o > 0; o >>= 1) v += __shfl_down(v, o, 64);
    return v;
}

// add the partner lane's value (lanes 2k <-> 2k+1) via DPP quad_perm[1,0,3,2]
__device__ __forceinline__ float pair_sum(float x) {
    int y = __builtin_amdgcn_mov_dpp(__float_as_int(x), 0xB1, 0xF, 0xF, true);
    return x + __int_as_float(y);
}

// 32-lane-group reduce (lanes of one LN row); offsets stay within 32-halves.
__device__ __forceinline__ float half_reduce_sum(float v) {
    #pragma unroll
    for (int o = 16; o > 0; o >>= 1) v += __shfl_xor(v, o, 64);
    return v;
}

// bare v_exp_f32 (2^x), no OCML fixup code
__device__ __forceinline__ float fast_exp2(float x) {
    return __builtin_amdgcn_exp2f(x);
}

// ---------------- GNN ----------------

// layer h pass; layer 0 gathers the embedding inline. s1/s2 pre-scaled by
// log2e (leaky_relu commutes with positive scale) so k_gnn_att skips the mul.
__global__ void k_gnn_h(const int* __restrict__ fing, const float* __restrict__ emb_fp,
                        float* __restrict__ xs, const float* __restrict__ fp_mask,
                        const float* __restrict__ Wg, const float* __restrict__ bg,
                        const float* __restrict__ aatt,
                        float* __restrict__ h, float* __restrict__ s1, float* __restrict__ s2,
                        int first) {
    int bn = blockIdx.x * blockDim.x + threadIdx.x;
    if (bn >= B * N) return;
    float x[DIM];
    if (first) {
        long base = (long)fing[bn] * DIM;
        #pragma unroll
        for (int d = 0; d < DIM; d++) { x[d] = emb_fp[base + d]; xs[bn * DIM + d] = x[d]; }
    } else {
        #pragma unroll
        for (int d = 0; d < DIM; d++) x[d] = xs[bn * DIM + d];
    }
    float m = fp_mask[bn];
    float a1 = 0.f, a2 = 0.f;
    #pragma unroll
    for (int j = 0; j < DIM; j++) {
        float acc = bg[j];
        #pragma unroll
        for (int d = 0; d < DIM; d++) acc += x[d] * Wg[d * DIM + j];
        acc = fmaxf(acc, 0.f) * m;
        h[bn * DIM + j] = acc;
        a1 += acc * aatt[j];
        a2 += acc * aatt[DIM + j];
    }
    s1[bn] = a1 * RLOG2E;
    s2[bn] = a2 * RLOG2E;
}

// 16 lane-groups of 16 lanes; each group owns one row. grid = B*(N/16), 256 thr.
// h repacked in LDS as [N][12] (48B rows, float4-aligned; s2 in slot 10) ->
// 3 ds_read_b128 per key instead of 11 scalar reads. No-max exp2 softmax.
__global__ void k_gnn_att(const float* __restrict__ h, const float* __restrict__ s1,
                          const float* __restrict__ s2, const int* __restrict__ adj,
                          float* __restrict__ xs) {
    int b  = blockIdx.x / (N / 16);
    int rg = blockIdx.x % (N / 16);
    int t = threadIdx.x;
    int g  = t >> 4;   // group 0..15
    int ll = t & 15;   // lane in group
    int i = rg * 16 + g;

    __shared__ float h_s[N * 12];    // 24KB (h[0..9], s2 at [10], pad [11])

    const float* hb = h + (long)b * N * DIM;
    for (int idx = t; idx < N * DIM; idx += 256) {
        int node = idx / DIM, d = idx - node * DIM;
        h_s[node * 12 + d] = hb[idx];
    }
    for (int j = t; j < N; j += 256) {
        h_s[j * 12 + 10] = s2[b * N + j];
        h_s[j * 12 + 11] = 0.f;
    }
    __syncthreads();

    float s1v = s1[b * N + i];            // already log2-scaled
    const int* adjrow = adj + ((long)b * N + i) * N;

    float sum = 0.f;
    float a[DIM];
    #pragma unroll
    for (int d = 0; d < DIM; d++) a[d] = 0.f;
    #pragma unroll
    for (int c = 0; c < 32; c++) {
        int j = c * 16 + ll;
        const float4* hp4 = (const float4*)&h_s[j * 12];
        float4 h0 = hp4[0], h1 = hp4[1], h2 = hp4[2];
        float xsc = s1v + h2.z;           // s2 packed at slot 10
        xsc = xsc > 0.f ? xsc : 0.01f * xsc;
        float e = (adjrow[j] > 0) ? xsc : NEGV;
        float p = fast_exp2(e);
        sum += p;
        a[0] += p * h0.x; a[1] += p * h0.y; a[2] += p * h0.z; a[3] += p * h0.w;
        a[4] += p * h1.x; a[5] += p * h1.y; a[6] += p * h1.z; a[7] += p * h1.w;
        a[8] += p * h2.x; a[9] += p * h2.y;
    }
    #pragma unroll
    for (int off = 1; off < 16; off <<= 1) {
        sum += __shfl_xor(sum, off, 64);
        #pragma unroll
        for (int d = 0; d < DIM; d++) a[d] += __shfl_xor(a[d], off, 64);
    }
    if (ll < DIM) {
        float av = a[0];
        if (ll == 1) av = a[1]; else if (ll == 2) av = a[2]; else if (ll == 3) av = a[3];
        else if (ll == 4) av = a[4]; else if (ll == 5) av = a[5]; else if (ll == 6) av = a[6];
        else if (ll == 7) av = a[7]; else if (ll == 8) av = a[8]; else if (ll == 9) av = a[9];
        xs[((long)b * N + i) * DIM + ll] += av / sum;
    }
}

// masked mean over nodes -> compound (hc moved into k_final)
__global__ void k_compound(const float* __restrict__ xs, const float* __restrict__ fp_mask,
                           float* __restrict__ compound) {
    int b = blockIdx.x;
    int t = threadIdx.x;  // 256
    int wid = t >> 6, lane = t & 63;
    float lacc[DIM];
    #pragma unroll
    for (int d = 0; d < DIM; d++) lacc[d] = 0.f;
    for (int n = t; n < N; n += 256) {
        float m = fp_mask[b * N + n];
        #pragma unroll
        for (int d = 0; d < DIM; d++) lacc[d] += xs[((long)b * N + n) * DIM + d] * m;
    }
    __shared__ float red[4][DIM];
    #pragma unroll
    for (int d = 0; d < DIM; d++) lacc[d] = wave_reduce_sum(lacc[d]);
    if (lane == 0) {
        #pragma unroll
        for (int d = 0; d < DIM; d++) red[wid][d] = lacc[d];
    }
    __syncthreads();
    if (t < DIM)
        compound[b * DIM + t] = (red[0][t] + red[1][t] + red[2][t] + red[3][t]) / (float)N;
}

// ---------------- Transformer ----------------

// embed + PE + LN1 + QKV projections fused. 16 rows/block, 384 threads.
__global__ void k_qkv(const int* __restrict__ words, const float* __restrict__ emb,
                      const float* __restrict__ ln1_g, const float* __restrict__ ln1_b,
                      const float* __restrict__ Wq, const float* __restrict__ bq,
                      const float* __restrict__ Wk, const float* __restrict__ bk,
                      const float* __restrict__ Wv, const float* __restrict__ bv,
                      float* __restrict__ x,
                      float* __restrict__ q, float* __restrict__ k, float* __restrict__ v) {
    long row0 = (long)blockIdx.x * RF;
    int t = threadIdx.x;  // 384
    __shared__ float x_s[RF * DM];
    __shared__ float xn_s[RF * DM];

    for (int i = t; i < RF * DM; i += 384) {
        int row = i >> 7, d = i & 127;
        long gr = row0 + row;
        int l = (int)(gr & (L - 1));
        int k2 = (d >> 1) * 2;
        double div = exp((double)k2 * (-log(10000.0) / (double)DM));
        double ang = (double)l * div;
        float pev = (d & 1) ? (float)cos(ang) : (float)sin(ang);
        float val = emb[(long)words[gr] * DM + d] * sqrtf(128.0f) + pev;
        x_s[i] = val;
        x[gr * DM + d] = val;
    }
    __syncthreads();

    if (t < 256) {   // LN1: 16-lane groups, 8 dims/lane (offsets stay in 16-lane groups)
        int row = t >> 4, ll = t & 15;
        float4 v1 = ((const float4*)&x_s[row * DM])[ll * 2];
        float4 v2 = ((const float4*)&x_s[row * DM])[ll * 2 + 1];
        float s = v1.x + v1.y + v1.z + v1.w + v2.x + v2.y + v2.z + v2.w;
        #pragma unroll
        for (int off = 1; off < 16; off <<= 1) s += __shfl_xor(s, off, 64);
        float mean = s / (float)DM;
        float d0 = v1.x - mean, d1 = v1.y - mean, d2 = v1.z - mean, d3 = v1.w - mean;
        float d4 = v2.x - mean, d5 = v2.y - mean, d6 = v2.z - mean, d7 = v2.w - mean;
        float qq = d0*d0 + d1*d1 + d2*d2 + d3*d3 + d4*d4 + d5*d5 + d6*d6 + d7*d7;
        #pragma unroll
        for (int off = 1; off < 16; off <<= 1) qq += __shfl_xor(qq, off, 64);
        float sd = sqrtf(qq / (float)(DM - 1)) + 1e-6f;
        const float4 g1 = ((const float4*)ln1_g)[ll * 2], g2 = ((const float4*)ln1_g)[ll * 2 + 1];
        const float4 b1 = ((const float4*)ln1_b)[ll * 2], b2 = ((const float4*)ln1_b)[ll * 2 + 1];
        ((float4*)&xn_s[row * DM])[ll * 2] = make_float4(
            g1.x * d0 / sd + b1.x, g1.y * d1 / sd + b1.y,
            g1.z * d2 / sd + b1.z, g1.w * d3 / sd + b1.w);
        ((float4*)&xn_s[row * DM])[ll * 2 + 1] = make_float4(
            g2.x * d4 / sd + b2.x, g2.y * d5 / sd + b2.y,
            g2.z * d6 / sd + b2.z, g2.w * d7 / sd + b2.w);
    }
    __syncthreads();

    int proj = t / DM;
    int j = t % DM;
    const float* W    = proj == 0 ? Wq : (proj == 1 ? Wk : Wv);
    const float* bias = proj == 0 ? bq : (proj == 1 ? bk : bv);
    float* out        = proj == 0 ? q  : (proj == 1 ? k  : v);
    float acc[RF];
    #pragma unroll
    for (int r = 0; r < RF; r++) acc[r] = bias[j];
    for (int d4 = 0; d4 < DM / 4; d4++) {
        float w0 = W[(4 * d4 + 0) * DM + j];
        float w1 = W[(4 * d4 + 1) * DM + j];
        float w2 = W[(4 * d4 + 2) * DM + j];
        float w3 = W[(4 * d4 + 3) * DM + j];
        #pragma unroll
        for (int r = 0; r < RF; r++) {
            float4 xv = ((const float4*)&xn_s[r * DM])[d4];
            acc[r] += xv.x * w0 + xv.y * w1 + xv.z * w2 + xv.w * w3;
        }
    }
    #pragma unroll
    for (int r = 0; r < RF; r++) {
        long row = row0 + r;
        int b = (int)(row / L), l = (int)(row % L);
        out[(((long)b * H + j / DK) * L + l) * DK + (j % DK)] = acc[r];
    }
}

// 2-slice flash attention, 4 key-segments: grid = B*H*(L/AQR2)*NSEG = 2048.
// No-max log2 softmax -> additive partials; k_oproj merges 4 segments.
// launch_bounds(256,8): 56 VGPR fits 8 waves/SIMD; raise resident blocks.
__global__ void __launch_bounds__(256, 8)
k_attn(const float* __restrict__ q, const float* __restrict__ k,
       const float* __restrict__ v, const float* __restrict__ wmask,
       float* __restrict__ attn_p, float* __restrict__ ssum_p) {
    int blk = blockIdx.x;
    int seg = blk & (NSEG - 1);
    int rest = blk >> 2;                 // NSEG = 4
    int qc = rest % (L / AQR2);
    int bh = rest / (L / AQR2);
    int b = bh / H, hh = bh % H;
    int t = threadIdx.x;   // 256
    int sl = t & 1;
    int r = t >> 1;
    int l = qc * AQR2 + r;
    int j00 = seg * KSEG;

    __shared__ float4 k_s[KSEG * 4];   // 8KB
    __shared__ float wm_s[KSEG];       // 0.5KB, additive mask 0 / -1.443e9
    const float4* kb4 = (const float4*)(k + (long)bh * L * DK) + (long)j00 * 4;
    for (int i = t; i < KSEG * 4; i += 256) k_s[i] = kb4[i];
    for (int j = t; j < KSEG; j += 256)
        wm_s[j] = (wmask[b * L + j00 + j] > 0.f) ? 0.f : -1.443e9f;
    __syncthreads();

    const float4* qp = (const float4*)(q + ((long)bh * L + l) * DK);
    float4 qa = qp[sl * 2], qb = qp[sl * 2 + 1];
    const float qsc = 0.25f * RLOG2E;
    qa.x *= qsc; qa.y *= qsc; qa.z *= qsc; qa.w *= qsc;
    qb.x *= qsc; qb.y *= qsc; qb.z *= qsc; qb.w *= qsc;

    const float4* vb4 = (const float4*)(v + (long)bh * L * DK) + (long)j00 * 4;

    float ssum = 0.f;
    float4 a0 = make_float4(0.f, 0.f, 0.f, 0.f), a1 = a0;

    for (int c = 0; c < KSEG / 8; c++) {
        int j0 = c * 8;
        float s8[8];
        #pragma unroll
        for (int jj = 0; jj < 8; jj++) {
            float4 ka = k_s[(j0 + jj) * 4 + sl * 2];
            float4 kb_ = k_s[(j0 + jj) * 4 + sl * 2 + 1];
            float part = qa.x * ka.x + qa.y * ka.y + qa.z * ka.z + qa.w * ka.w
                       + qb.x * kb_.x + qb.y * kb_.y + qb.z * kb_.z + qb.w * kb_.w;
            s8[jj] = pair_sum(part);
        }
        const float4* mp = (const float4*)&wm_s[j0];
        float4 ma = mp[0], mb = mp[1];
        s8[0] += ma.x; s8[1] += ma.y; s8[2] += ma.z; s8[3] += ma.w;
        s8[4] += mb.x; s8[5] += mb.y; s8[6] += mb.z; s8[7] += mb.w;

        #pragma unroll
        for (int jj = 0; jj < 8; jj++) {
            float p = fast_exp2(s8[jj]);
            ssum += p;
            float4 va  = vb4[(j0 + jj) * 4 + sl * 2];
            float4 vb2 = vb4[(j0 + jj) * 4 + sl * 2 + 1];
            a0.x += p * va.x;  a0.y += p * va.y;  a0.z += p * va.z;  a0.w += p * va.w;
            a1.x += p * vb2.x; a1.y += p * vb2.y; a1.z += p * vb2.z; a1.w += p * vb2.w;
        }
    }

    // unnormalized partial out
    float4* outp = (float4*)(attn_p + (((long)seg * B + b) * L + l) * DM + hh * DK);
    outp[sl * 2]     = a0;
    outp[sl * 2 + 1] = a1;
    if (sl == 0) ssum_p[(((long)seg * B + b) * H + hh) * L + l] = ssum;
}

// x += merge(attn partials) @ Wo + bo ; 16 rows/block, 128 threads.
__global__ void k_oproj(const float* __restrict__ attn_p, const float* __restrict__ ssum_p,
                        const float* __restrict__ Wo, const float* __restrict__ bo,
                        float* __restrict__ x) {
    long row0 = (long)blockIdx.x * RF;
    int t = threadIdx.x;  // 128
    int b = (int)(row0 / L);
    int l0 = (int)(row0 % L);

    __shared__ float a_s[RF * DM];
    __shared__ float inv_s[RF][H];

    {   // t indexes (row, head) exactly: 16*8 = 128
        int row = t >> 3, hh = t & 7;
        float s = 0.f;
        #pragma unroll
        for (int sg = 0; sg < NSEG; sg++)
            s += ssum_p[(((long)sg * B + b) * H + hh) * L + (l0 + row)];
        inv_s[row][hh] = 1.f / s;
    }
    __syncthreads();

    const float4* p0 = (const float4*)(attn_p + (((long)0 * B + b) * L + l0) * DM);
    const float4* p1 = (const float4*)(attn_p + (((long)1 * B + b) * L + l0) * DM);
    const float4* p2 = (const float4*)(attn_p + (((long)2 * B + b) * L + l0) * DM);
    const float4* p3 = (const float4*)(attn_p + (((long)3 * B + b) * L + l0) * DM);
    for (int i = t; i < RF * DM / 4; i += 128) {
        float4 a0 = p0[i], a1 = p1[i], a2 = p2[i], a3 = p3[i];
        int row = i >> 5;
        int hh = (i & 31) >> 2;
        float inv = inv_s[row][hh];
        ((float4*)a_s)[i] = make_float4((a0.x + a1.x + a2.x + a3.x) * inv,
                                        (a0.y + a1.y + a2.y + a3.y) * inv,
                                        (a0.z + a1.z + a2.z + a3.z) * inv,
                                        (a0.w + a1.w + a2.w + a3.w) * inv);
    }
    __syncthreads();

    float acc[RF];
    #pragma unroll
    for (int r = 0; r < RF; r++) acc[r] = bo[t];
    for (int d4 = 0; d4 < DM / 4; d4++) {
        float w0 = Wo[(4 * d4 + 0) * DM + t];
        float w1 = Wo[(4 * d4 + 1) * DM + t];
        float w2 = Wo[(4 * d4 + 2) * DM + t];
        float w3 = Wo[(4 * d4 + 3) * DM + t];
        #pragma unroll
        for (int r = 0; r < RF; r++) {
            float4 av = ((const float4*)&a_s[r * DM])[d4];
            acc[r] += av.x * w0 + av.y * w1 + av.z * w2 + av.w * w3;
        }
    }
    #pragma unroll
    for (int r = 0; r < RF; r++) x[(row0 + r) * DM + t] += acc[r];
}

// fused tail: LN2 -> FFN -> +x -> LNf -> relu@Wtout -> @Watt/relu -> hp.
__global__ void k_ffn_fused(const float* __restrict__ x,
                            const float* __restrict__ ln2_g, const float* __restrict__ ln2_b,
                            const float* __restrict__ W1, const float* __restrict__ b1,
                            const float* __restrict__ W2, const float* __restrict__ b2,
                            const float* __restrict__ lnf_g, const float* __restrict__ lnf_b,
                            const float* __restrict__ Wtout, const float* __restrict__ btout,
                            const float* __restrict__ Watt, const float* __restrict__ batt,
                            float* __restrict__ hp) {
    long row0 = (long)blockIdx.x * RF;
    int t = threadIdx.x;  // 512

    __shared__ float x_s[RF][DM];       // 8 KB
    __shared__ float xn_s[RF][DM];      // 8 KB
    __shared__ float h_s[RF][DFF];      // 32 KB
    __shared__ float r_s[RF][DM + 4];   // 8.25 KB
    __shared__ float wt_s[DM * DIM];    // 5 KB
    __shared__ float wa_s[DIM * DIM];
    __shared__ float bt_s[DIM], ba_s[DIM];
    __shared__ float wv_s[RF][DIM];

    {
        float4 xv = ((const float4*)(x + row0 * DM))[t];
        ((float4*)&x_s[0][0])[t] = xv;
        for (int i = t; i < DM * DIM; i += 512) wt_s[i] = Wtout[i];
        for (int i = t; i < DIM * DIM; i += 512) wa_s[i] = Watt[i];
        if (t < DIM) { bt_s[t] = btout[t]; ba_s[t] = batt[t]; }
    }
    __syncthreads();

    {
        int row = t >> 5, c = t & 31;
        float4 v = ((const float4*)&x_s[row][0])[c];
        float s = half_reduce_sum(v.x + v.y + v.z + v.w);
        float mean = s / (float)DM;
        float4 dv = make_float4(v.x - mean, v.y - mean, v.z - mean, v.w - mean);
        float q = half_reduce_sum(dv.x * dv.x + dv.y * dv.y + dv.z * dv.z + dv.w * dv.w);
        float sd = sqrtf(q / (float)(DM - 1)) + 1e-6f;
        const float4 g4 = ((const float4*)ln2_g)[c];
        const float4 b4 = ((const float4*)ln2_b)[c];
        ((float4*)&xn_s[row][0])[c] = make_float4(
            g4.x * dv.x / sd + b4.x, g4.y * dv.y / sd + b4.y,
            g4.z * dv.z / sd + b4.z, g4.w * dv.w / sd + b4.w);
    }
    __syncthreads();

    {
        float acc[RF];
        #pragma unroll
        for (int r = 0; r < RF; r++) acc[r] = b1[t];
        for (int d4 = 0; d4 < DM / 4; d4++) {
            float w0 = W1[(4 * d4 + 0) * DFF + t];
            float w1 = W1[(4 * d4 + 1) * DFF + t];
            float w2 = W1[(4 * d4 + 2) * DFF + t];
            float w3 = W1[(4 * d4 + 3) * DFF + t];
            #pragma unroll
            for (int r = 0; r < RF; r++) {
                float4 xv = ((const float4*)&xn_s[r][0])[d4];
                acc[r] += xv.x * w0 + xv.y * w1 + xv.z * w2 + xv.w * w3;
            }
        }
        #pragma unroll
        for (int r = 0; r < RF; r++) h_s[r][t] = fmaxf(acc[r], 0.f);
    }
    __syncthreads();

    {
        int col = t & 127, rq = t >> 7;
        float acc2[4];
        #pragma unroll
        for (int rr = 0; rr < 4; rr++) acc2[rr] = b2[col];
        for (int f4 = 0; f4 < DFF / 4; f4++) {
            float w0 = W2[(4 * f4 + 0) * DM + col];
            float w1 = W2[(4 * f4 + 1) * DM + col];
            float w2 = W2[(4 * f4 + 2) * DM + col];
            float w3 = W2[(4 * f4 + 3) * DM + col];
            #pragma unroll
            for (int rr = 0; rr < 4; rr++) {
                float4 hv = ((const float4*)&h_s[rq * 4 + rr][0])[f4];
                acc2[rr] += hv.x * w0 + hv.y * w1 + hv.z * w2 + hv.w * w3;
            }
        }
        __syncthreads();
        #pragma unroll
        for (int rr = 0; rr < 4; rr++) {
            int row = rq * 4 + rr;
            xn_s[row][col] = x_s[row][col] + acc2[rr];
        }
    }
    __syncthreads();

    {
        int row = t >> 5, c = t & 31;
        float4 v = ((const float4*)&xn_s[row][0])[c];
        float s = half_reduce_sum(v.x + v.y + v.z + v.w);
        float mean = s / (float)DM;
        float4 dv = make_float4(v.x - mean, v.y - mean, v.z - mean, v.w - mean);
        float q = half_reduce_sum(dv.x * dv.x + dv.y * dv.y + dv.z * dv.z + dv.w * dv.w);
        float sd = sqrtf(q / (float)(DM - 1)) + 1e-6f;
        const float4 g4 = ((const float4*)lnf_g)[c];
        const float4 b4 = ((const float4*)lnf_b)[c];
        r_s[row][4 * c + 0] = fmaxf(g4.x * dv.x / sd + b4.x, 0.f);
        r_s[row][4 * c + 1] = fmaxf(g4.y * dv.y / sd + b4.y, 0.f);
        r_s[row][4 * c + 2] = fmaxf(g4.z * dv.z / sd + b4.z, 0.f);
        r_s[row][4 * c + 3] = fmaxf(g4.w * dv.w / sd + b4.w, 0.f);
    }
    __syncthreads();

    if (t < RF * DIM) {
        int row = t / DIM, o = t % DIM;
        float acc = bt_s[o];
        for (int d = 0; d < DM; d++) acc += r_s[row][d] * wt_s[d * DIM + o];
        wv_s[row][o] = acc;
    }
    __syncthreads();

    if (t < RF * DIM) {
        int row = t / DIM, o = t % DIM;
        float acc = ba_s[o];
        #pragma unroll
        for (int e = 0; e < DIM; e++) acc += wv_s[row][e] * wa_s[e * DIM + o];
        hp[(row0 + row) * DIM + o] = fmaxf(acc, 0.f);
    }
}

// final: hc = relu(compound@Watt+batt); w = tanh(hc.hp); protein mean; MLP; out.
__global__ void k_final(const float* __restrict__ hp, const float* __restrict__ compound,
                        const float* __restrict__ Watt, const float* __restrict__ batt,
                        const float* __restrict__ Wout, const float* __restrict__ bout,
                        const float* __restrict__ Wint, const float* __restrict__ bint,
                        float* __restrict__ out) {
    int b = blockIdx.x;
    int t = threadIdx.x;  // 256
    int wid = t >> 6, lane = t & 63;

    __shared__ float wout_s[LO * 2 * DIM * 2 * DIM];
    __shared__ float bout_s[LO * 2 * DIM];
    __shared__ float wint_s[2 * DIM * 2];
    __shared__ float bint_s[2];
    __shared__ float comp_s[DIM];
    __shared__ float hc_s[DIM];
    __shared__ float red[4][DIM];
    __shared__ float cat_s[2 * DIM];
    __shared__ float tmp_s[2 * DIM];

    for (int i = t; i < LO * 2 * DIM * 2 * DIM; i += 256) wout_s[i] = Wout[i];
    for (int i = t; i < LO * 2 * DIM; i += 256) bout_s[i] = bout[i];
    for (int i = t; i < 2 * DIM * 2; i += 256) wint_s[i] = Wint[i];
    if (t < 2) bint_s[t] = bint[t];
    if (t < DIM) comp_s[t] = compound[b * DIM + t];
    __syncthreads();
    if (t < DIM) {
        float acc = batt[t];
        #pragma unroll
        for (int e = 0; e < DIM; e++) acc += comp_s[e] * Watt[e * DIM + t];
        hc_s[t] = fmaxf(acc, 0.f);
    }
    __syncthreads();

    float lacc[DIM];
    #pragma unroll
    for (int e = 0; e < DIM; e++) lacc[e] = 0.f;
    for (int l = t; l < L; l += 256) {
        const float* hpl = hp + ((long)b * L + l) * DIM;
        float hv[DIM];
        float dot = 0.f;
        #pragma unroll
        for (int e = 0; e < DIM; e++) { hv[e] = hpl[e]; dot += hc_s[e] * hv[e]; }
        float w = tanhf(dot);
        #pragma unroll
        for (int e = 0; e < DIM; e++) lacc[e] += w * hv[e];
    }
    #pragma unroll
    for (int e = 0; e < DIM; e++) lacc[e] = wave_reduce_sum(lacc[e]);
    if (lane == 0) {
        #pragma unroll
        for (int e = 0; e < DIM; e++) red[wid][e] = lacc[e];
    }
    __syncthreads();
    if (t < DIM) {
        cat_s[t] = comp_s[t];
        cat_s[DIM + t] = (red[0][t] + red[1][t] + red[2][t] + red[3][t]) / (float)L;
    }
    __syncthreads();

    for (int j = 0; j < LO; j++) {
        float acc = 0.f;
        if (t < 2 * DIM) {
            acc = bout_s[j * 2 * DIM + t];
            #pragma unroll
            for (int e = 0; e < 2 * DIM; e++)
                acc += cat_s[e] * wout_s[j * 2 * DIM * 2 * DIM + e * 2 * DIM + t];
            acc = fmaxf(acc, 0.f);
            tmp_s[t] = acc;
        }
        __syncthreads();
        if (t < 2 * DIM) cat_s[t] = tmp_s[t];
        __syncthreads();
    }
    if (t < 2) {
        float o = bint_s[t];
        #pragma unroll
        for (int e = 0; e < 2 * DIM; e++) o += cat_s[e] * wint_s[e * 2 + t];
        out[b * 2 + t] = o;
    }
}

extern "C" void kernel_launch(void* const* d_in, const int* in_sizes, int n_in,
                              void* d_out, int out_size, void* d_ws, size_t ws_size,
                              hipStream_t stream) {
    (void)in_sizes; (void)n_in; (void)out_size; (void)ws_size;
    const int*   fingerprints = (const int*)d_in[0];
    const float* fp_mask      = (const float*)d_in[1];
    const int*   adjacency    = (const int*)d_in[2];
    const int*   words        = (const int*)d_in[3];
    const float* words_mask   = (const float*)d_in[4];
    const float* emb_fp       = (const float*)d_in[5];
    const float* emb_word     = (const float*)d_in[6];
    const float* Wg   = (const float*)d_in[7];
    const float* bg   = (const float*)d_in[8];
    const float* attn_a = (const float*)d_in[9];
    const float* Wq = (const float*)d_in[10];
    const float* bq = (const float*)d_in[11];
    const float* Wk = (const float*)d_in[12];
    const float* bk = (const float*)d_in[13];
    const float* Wv = (const float*)d_in[14];
    const float* bv = (const float*)d_in[15];
    const float* Wo = (const float*)d_in[16];
    const float* bo = (const float*)d_in[17];
    const float* ln1_g = (const float*)d_in[18];
    const float* ln1_b = (const float*)d_in[19];
    const float* ln2_g = (const float*)d_in[20];
    const float* ln2_b = (const float*)d_in[21];
    const float* lnf_g = (const float*)d_in[22];
    const float* lnf_b = (const float*)d_in[23];
    const float* W1 = (const float*)d_in[24];
    const float* b1 = (const float*)d_in[25];
    const float* W2 = (const float*)d_in[26];
    const float* b2 = (const float*)d_in[27];
    const float* Wtout = (const float*)d_in[28];
    const float* btout = (const float*)d_in[29];
    const float* Watt  = (const float*)d_in[30];
    const float* batt  = (const float*)d_in[31];
    const float* Wout  = (const float*)d_in[32];
    const float* bout  = (const float*)d_in[33];
    const float* Wint  = (const float*)d_in[34];
    const float* bint  = (const float*)d_in[35];
    float* out = (float*)d_out;

    float* w = (float*)d_ws;
    float* xs = w;        w += B * N * DIM;
    float* h  = w;        w += B * N * DIM;
    float* s1 = w;        w += B * N;
    float* s2 = w;        w += B * N;
    float* compound = w;  w += B * DIM;
    float* x  = w;        w += (long)B * L * DM;
    float* qb = w;        w += (long)B * H * L * DK;
    float* kb = w;        w += (long)B * H * L * DK;
    float* vb = w;        w += (long)B * H * L * DK;
    float* attn_p = w;    w += (long)NSEG * B * L * DM;
    float* ssum_p = w;    w += (long)NSEG * B * H * L;
    float* hp = w;        w += (long)B * L * DIM;

    // ---- GNN ----
    for (int i = 0; i < LG; i++) {
        k_gnn_h<<<(B * N + 255) / 256, 256, 0, stream>>>(
            fingerprints, emb_fp, xs, fp_mask,
            Wg + i * DIM * DIM, bg + i * DIM, attn_a + i * 2 * DIM, h, s1, s2, i == 0);
        k_gnn_att<<<B * (N / 16), 256, 0, stream>>>(h, s1, s2, adjacency, xs);
    }
    k_compound<<<B, 256, 0, stream>>>(xs, fp_mask, compound);

    // ---- Transformer ----
    k_qkv<<<B * L / RF, 3 * DM, 0, stream>>>(words, emb_word, ln1_g, ln1_b,
                                             Wq, bq, Wk, bk, Wv, bv, x, qb, kb, vb);
    k_attn<<<B * H * (L / AQR2) * NSEG, 256, 0, stream>>>(qb, kb, vb, words_mask, attn_p, ssum_p);
    k_oproj<<<B * L / RF, DM, 0, stream>>>(attn_p, ssum_p, Wo, bo, x);
    k_ffn_fused<<<B * L / RF, DFF, 0, stream>>>(x, ln2_g, ln2_b, W1, b1, W2, b2,
                                                lnf_g, lnf_b, Wtout, btout, Watt, batt, hp);
    k_final<<<B, 256, 0, stream>>>(hp, compound, Watt, batt,
                                   Wout, bout, Wint, bint, out);
}

// Round 22
// 221.693 us; speedup vs baseline: 2.1774x; 2.1774x over previous
//
#include <hip/hip_runtime.h>
#include <hip/hip_bf16.h>
#include <math.h>

#define B 16
#define N 512
#define L 512
#define DIM 10
#define DM 128
#define H 8
#define DK 16
#define DFF 512
#define LG 3
#define LO 3
#define NEGV -9.0e15f
#define RF 16      // rows per block (ffn/qkv/oproj)
#define AQR2 128   // q-rows per attn block (2-slice)
#define KSEG 128   // keys per attn segment
#define NSEG (L / KSEG)
#define RLOG2E 1.44269504f

__device__ __forceinline__ float wave_reduce_sum(float v) {
    #pragma unroll
    for (int o = 32; o > 0; o >>= 1) v += __shfl_down(v, o, 64);
    return v;
}

// add the partner lane's value (lanes 2k <-> 2k+1) via DPP quad_perm[1,0,3,2]
__device__ __forceinline__ float pair_sum(float x) {
    int y = __builtin_amdgcn_mov_dpp(__float_as_int(x), 0xB1, 0xF, 0xF, true);
    return x + __int_as_float(y);
}

// 32-lane-group reduce (lanes of one LN row); offsets stay within 32-halves.
__device__ __forceinline__ float half_reduce_sum(float v) {
    #pragma unroll
    for (int o = 16; o > 0; o >>= 1) v += __shfl_xor(v, o, 64);
    return v;
}

// bare v_exp_f32 (2^x), no OCML fixup code
__device__ __forceinline__ float fast_exp2(float x) {
    return __builtin_amdgcn_exp2f(x);
}

// ---------------- GNN ----------------

// layer h pass; layer 0 gathers the embedding inline. s1/s2 pre-scaled by
// log2e (leaky_relu commutes with positive scale) so k_gnn_att skips the mul.
__global__ void k_gnn_h(const int* __restrict__ fing, const float* __restrict__ emb_fp,
                        float* __restrict__ xs, const float* __restrict__ fp_mask,
                        const float* __restrict__ Wg, const float* __restrict__ bg,
                        const float* __restrict__ aatt,
                        float* __restrict__ h, float* __restrict__ s1, float* __restrict__ s2,
                        int first) {
    int bn = blockIdx.x * blockDim.x + threadIdx.x;
    if (bn >= B * N) return;
    float x[DIM];
    if (first) {
        long base = (long)fing[bn] * DIM;
        #pragma unroll
        for (int d = 0; d < DIM; d++) { x[d] = emb_fp[base + d]; xs[bn * DIM + d] = x[d]; }
    } else {
        #pragma unroll
        for (int d = 0; d < DIM; d++) x[d] = xs[bn * DIM + d];
    }
    float m = fp_mask[bn];
    float a1 = 0.f, a2 = 0.f;
    #pragma unroll
    for (int j = 0; j < DIM; j++) {
        float acc = bg[j];
        #pragma unroll
        for (int d = 0; d < DIM; d++) acc += x[d] * Wg[d * DIM + j];
        acc = fmaxf(acc, 0.f) * m;
        h[bn * DIM + j] = acc;
        a1 += acc * aatt[j];
        a2 += acc * aatt[DIM + j];
    }
    s1[bn] = a1 * RLOG2E;
    s2[bn] = a2 * RLOG2E;
}

// 16 lane-groups of 16 lanes; each group owns one row. grid = B*(N/16), 256 thr.
// h repacked in LDS as [N][12] (48B rows, float4-aligned; s2 in slot 10) ->
// 3 ds_read_b128 per key instead of 11 scalar reads. No-max exp2 softmax.
__global__ void k_gnn_att(const float* __restrict__ h, const float* __restrict__ s1,
                          const float* __restrict__ s2, const int* __restrict__ adj,
                          float* __restrict__ xs) {
    int b  = blockIdx.x / (N / 16);
    int rg = blockIdx.x % (N / 16);
    int t = threadIdx.x;
    int g  = t >> 4;   // group 0..15
    int ll = t & 15;   // lane in group
    int i = rg * 16 + g;

    __shared__ float h_s[N * 12];    // 24KB (h[0..9], s2 at [10], pad [11])

    const float* hb = h + (long)b * N * DIM;
    for (int idx = t; idx < N * DIM; idx += 256) {
        int node = idx / DIM, d = idx - node * DIM;
        h_s[node * 12 + d] = hb[idx];
    }
    for (int j = t; j < N; j += 256) {
        h_s[j * 12 + 10] = s2[b * N + j];
        h_s[j * 12 + 11] = 0.f;
    }
    __syncthreads();

    float s1v = s1[b * N + i];            // already log2-scaled
    const int* adjrow = adj + ((long)b * N + i) * N;

    float sum = 0.f;
    float a[DIM];
    #pragma unroll
    for (int d = 0; d < DIM; d++) a[d] = 0.f;
    #pragma unroll
    for (int c = 0; c < 32; c++) {
        int j = c * 16 + ll;
        const float4* hp4 = (const float4*)&h_s[j * 12];
        float4 h0 = hp4[0], h1 = hp4[1], h2 = hp4[2];
        float xsc = s1v + h2.z;           // s2 packed at slot 10
        xsc = xsc > 0.f ? xsc : 0.01f * xsc;
        float e = (adjrow[j] > 0) ? xsc : NEGV;
        float p = fast_exp2(e);
        sum += p;
        a[0] += p * h0.x; a[1] += p * h0.y; a[2] += p * h0.z; a[3] += p * h0.w;
        a[4] += p * h1.x; a[5] += p * h1.y; a[6] += p * h1.z; a[7] += p * h1.w;
        a[8] += p * h2.x; a[9] += p * h2.y;
    }
    #pragma unroll
    for (int off = 1; off < 16; off <<= 1) {
        sum += __shfl_xor(sum, off, 64);
        #pragma unroll
        for (int d = 0; d < DIM; d++) a[d] += __shfl_xor(a[d], off, 64);
    }
    if (ll < DIM) {
        float av = a[0];
        if (ll == 1) av = a[1]; else if (ll == 2) av = a[2]; else if (ll == 3) av = a[3];
        else if (ll == 4) av = a[4]; else if (ll == 5) av = a[5]; else if (ll == 6) av = a[6];
        else if (ll == 7) av = a[7]; else if (ll == 8) av = a[8]; else if (ll == 9) av = a[9];
        xs[((long)b * N + i) * DIM + ll] += av / sum;
    }
}

// masked mean over nodes -> compound (hc moved into k_final)
__global__ void k_compound(const float* __restrict__ xs, const float* __restrict__ fp_mask,
                           float* __restrict__ compound) {
    int b = blockIdx.x;
    int t = threadIdx.x;  // 256
    int wid = t >> 6, lane = t & 63;
    float lacc[DIM];
    #pragma unroll
    for (int d = 0; d < DIM; d++) lacc[d] = 0.f;
    for (int n = t; n < N; n += 256) {
        float m = fp_mask[b * N + n];
        #pragma unroll
        for (int d = 0; d < DIM; d++) lacc[d] += xs[((long)b * N + n) * DIM + d] * m;
    }
    __shared__ float red[4][DIM];
    #pragma unroll
    for (int d = 0; d < DIM; d++) lacc[d] = wave_reduce_sum(lacc[d]);
    if (lane == 0) {
        #pragma unroll
        for (int d = 0; d < DIM; d++) red[wid][d] = lacc[d];
    }
    __syncthreads();
    if (t < DIM)
        compound[b * DIM + t] = (red[0][t] + red[1][t] + red[2][t] + red[3][t]) / (float)N;
}

// ---------------- Transformer ----------------

// embed + PE + LN1 + QKV projections fused. 16 rows/block, 384 threads.
__global__ void k_qkv(const int* __restrict__ words, const float* __restrict__ emb,
                      const float* __restrict__ ln1_g, const float* __restrict__ ln1_b,
                      const float* __restrict__ Wq, const float* __restrict__ bq,
                      const float* __restrict__ Wk, const float* __restrict__ bk,
                      const float* __restrict__ Wv, const float* __restrict__ bv,
                      float* __restrict__ x,
                      float* __restrict__ q, float* __restrict__ k, float* __restrict__ v) {
    long row0 = (long)blockIdx.x * RF;
    int t = threadIdx.x;  // 384
    __shared__ float x_s[RF * DM];
    __shared__ float xn_s[RF * DM];

    for (int i = t; i < RF * DM; i += 384) {
        int row = i >> 7, d = i & 127;
        long gr = row0 + row;
        int l = (int)(gr & (L - 1));
        int k2 = (d >> 1) * 2;
        double div = exp((double)k2 * (-log(10000.0) / (double)DM));
        double ang = (double)l * div;
        float pev = (d & 1) ? (float)cos(ang) : (float)sin(ang);
        float val = emb[(long)words[gr] * DM + d] * sqrtf(128.0f) + pev;
        x_s[i] = val;
        x[gr * DM + d] = val;
    }
    __syncthreads();

    if (t < 256) {   // LN1: 16-lane groups, 8 dims/lane (offsets stay in 16-lane groups)
        int row = t >> 4, ll = t & 15;
        float4 v1 = ((const float4*)&x_s[row * DM])[ll * 2];
        float4 v2 = ((const float4*)&x_s[row * DM])[ll * 2 + 1];
        float s = v1.x + v1.y + v1.z + v1.w + v2.x + v2.y + v2.z + v2.w;
        #pragma unroll
        for (int off = 1; off < 16; off <<= 1) s += __shfl_xor(s, off, 64);
        float mean = s / (float)DM;
        float d0 = v1.x - mean, d1 = v1.y - mean, d2 = v1.z - mean, d3 = v1.w - mean;
        float d4 = v2.x - mean, d5 = v2.y - mean, d6 = v2.z - mean, d7 = v2.w - mean;
        float qq = d0*d0 + d1*d1 + d2*d2 + d3*d3 + d4*d4 + d5*d5 + d6*d6 + d7*d7;
        #pragma unroll
        for (int off = 1; off < 16; off <<= 1) qq += __shfl_xor(qq, off, 64);
        float sd = sqrtf(qq / (float)(DM - 1)) + 1e-6f;
        const float4 g1 = ((const float4*)ln1_g)[ll * 2], g2 = ((const float4*)ln1_g)[ll * 2 + 1];
        const float4 b1 = ((const float4*)ln1_b)[ll * 2], b2 = ((const float4*)ln1_b)[ll * 2 + 1];
        ((float4*)&xn_s[row * DM])[ll * 2] = make_float4(
            g1.x * d0 / sd + b1.x, g1.y * d1 / sd + b1.y,
            g1.z * d2 / sd + b1.z, g1.w * d3 / sd + b1.w);
        ((float4*)&xn_s[row * DM])[ll * 2 + 1] = make_float4(
            g2.x * d4 / sd + b2.x, g2.y * d5 / sd + b2.y,
            g2.z * d6 / sd + b2.z, g2.w * d7 / sd + b2.w);
    }
    __syncthreads();

    int proj = t / DM;
    int j = t % DM;
    const float* W    = proj == 0 ? Wq : (proj == 1 ? Wk : Wv);
    const float* bias = proj == 0 ? bq : (proj == 1 ? bk : bv);
    float* out        = proj == 0 ? q  : (proj == 1 ? k  : v);
    float acc[RF];
    #pragma unroll
    for (int r = 0; r < RF; r++) acc[r] = bias[j];
    for (int d4 = 0; d4 < DM / 4; d4++) {
        float w0 = W[(4 * d4 + 0) * DM + j];
        float w1 = W[(4 * d4 + 1) * DM + j];
        float w2 = W[(4 * d4 + 2) * DM + j];
        float w3 = W[(4 * d4 + 3) * DM + j];
        #pragma unroll
        for (int r = 0; r < RF; r++) {
            float4 xv = ((const float4*)&xn_s[r * DM])[d4];
            acc[r] += xv.x * w0 + xv.y * w1 + xv.z * w2 + xv.w * w3;
        }
    }
    #pragma unroll
    for (int r = 0; r < RF; r++) {
        long row = row0 + r;
        int b = (int)(row / L), l = (int)(row % L);
        out[(((long)b * H + j / DK) * L + l) * DK + (j % DK)] = acc[r];
    }
}

// 2-slice flash attention, 4 key-segments: grid = B*H*(L/AQR2)*NSEG = 2048.
// No-max log2 softmax -> additive partials; k_oproj merges 4 segments.
// launch_bounds(256,4): the proven setting — (256,8) forced a 32-VGPR cap
// and catastrophic spill (r21); do not raise.
__global__ void __launch_bounds__(256, 4)
k_attn(const float* __restrict__ q, const float* __restrict__ k,
       const float* __restrict__ v, const float* __restrict__ wmask,
       float* __restrict__ attn_p, float* __restrict__ ssum_p) {
    int blk = blockIdx.x;
    int seg = blk & (NSEG - 1);
    int rest = blk >> 2;                 // NSEG = 4
    int qc = rest % (L / AQR2);
    int bh = rest / (L / AQR2);
    int b = bh / H, hh = bh % H;
    int t = threadIdx.x;   // 256
    int sl = t & 1;
    int r = t >> 1;
    int l = qc * AQR2 + r;
    int j00 = seg * KSEG;

    __shared__ float4 k_s[KSEG * 4];   // 8KB
    __shared__ float wm_s[KSEG];       // 0.5KB, additive mask 0 / -1.443e9
    const float4* kb4 = (const float4*)(k + (long)bh * L * DK) + (long)j00 * 4;
    for (int i = t; i < KSEG * 4; i += 256) k_s[i] = kb4[i];
    for (int j = t; j < KSEG; j += 256)
        wm_s[j] = (wmask[b * L + j00 + j] > 0.f) ? 0.f : -1.443e9f;
    __syncthreads();

    const float4* qp = (const float4*)(q + ((long)bh * L + l) * DK);
    float4 qa = qp[sl * 2], qb = qp[sl * 2 + 1];
    const float qsc = 0.25f * RLOG2E;
    qa.x *= qsc; qa.y *= qsc; qa.z *= qsc; qa.w *= qsc;
    qb.x *= qsc; qb.y *= qsc; qb.z *= qsc; qb.w *= qsc;

    const float4* vb4 = (const float4*)(v + (long)bh * L * DK) + (long)j00 * 4;

    float ssum = 0.f;
    float4 a0 = make_float4(0.f, 0.f, 0.f, 0.f), a1 = a0;

    for (int c = 0; c < KSEG / 8; c++) {
        int j0 = c * 8;
        float s8[8];
        #pragma unroll
        for (int jj = 0; jj < 8; jj++) {
            float4 ka = k_s[(j0 + jj) * 4 + sl * 2];
            float4 kb_ = k_s[(j0 + jj) * 4 + sl * 2 + 1];
            float part = qa.x * ka.x + qa.y * ka.y + qa.z * ka.z + qa.w * ka.w
                       + qb.x * kb_.x + qb.y * kb_.y + qb.z * kb_.z + qb.w * kb_.w;
            s8[jj] = pair_sum(part);
        }
        const float4* mp = (const float4*)&wm_s[j0];
        float4 ma = mp[0], mb = mp[1];
        s8[0] += ma.x; s8[1] += ma.y; s8[2] += ma.z; s8[3] += ma.w;
        s8[4] += mb.x; s8[5] += mb.y; s8[6] += mb.z; s8[7] += mb.w;

        #pragma unroll
        for (int jj = 0; jj < 8; jj++) {
            float p = fast_exp2(s8[jj]);
            ssum += p;
            float4 va  = vb4[(j0 + jj) * 4 + sl * 2];
            float4 vb2 = vb4[(j0 + jj) * 4 + sl * 2 + 1];
            a0.x += p * va.x;  a0.y += p * va.y;  a0.z += p * va.z;  a0.w += p * va.w;
            a1.x += p * vb2.x; a1.y += p * vb2.y; a1.z += p * vb2.z; a1.w += p * vb2.w;
        }
    }

    // unnormalized partial out
    float4* outp = (float4*)(attn_p + (((long)seg * B + b) * L + l) * DM + hh * DK);
    outp[sl * 2]     = a0;
    outp[sl * 2 + 1] = a1;
    if (sl == 0) ssum_p[(((long)seg * B + b) * H + hh) * L + l] = ssum;
}

// x += merge(attn partials) @ Wo + bo ; 16 rows/block, 128 threads.
__global__ void k_oproj(const float* __restrict__ attn_p, const float* __restrict__ ssum_p,
                        const float* __restrict__ Wo, const float* __restrict__ bo,
                        float* __restrict__ x) {
    long row0 = (long)blockIdx.x * RF;
    int t = threadIdx.x;  // 128
    int b = (int)(row0 / L);
    int l0 = (int)(row0 % L);

    __shared__ float a_s[RF * DM];
    __shared__ float inv_s[RF][H];

    {   // t indexes (row, head) exactly: 16*8 = 128
        int row = t >> 3, hh = t & 7;
        float s = 0.f;
        #pragma unroll
        for (int sg = 0; sg < NSEG; sg++)
            s += ssum_p[(((long)sg * B + b) * H + hh) * L + (l0 + row)];
        inv_s[row][hh] = 1.f / s;
    }
    __syncthreads();

    const float4* p0 = (const float4*)(attn_p + (((long)0 * B + b) * L + l0) * DM);
    const float4* p1 = (const float4*)(attn_p + (((long)1 * B + b) * L + l0) * DM);
    const float4* p2 = (const float4*)(attn_p + (((long)2 * B + b) * L + l0) * DM);
    const float4* p3 = (const float4*)(attn_p + (((long)3 * B + b) * L + l0) * DM);
    for (int i = t; i < RF * DM / 4; i += 128) {
        float4 a0 = p0[i], a1 = p1[i], a2 = p2[i], a3 = p3[i];
        int row = i >> 5;
        int hh = (i & 31) >> 2;
        float inv = inv_s[row][hh];
        ((float4*)a_s)[i] = make_float4((a0.x + a1.x + a2.x + a3.x) * inv,
                                        (a0.y + a1.y + a2.y + a3.y) * inv,
                                        (a0.z + a1.z + a2.z + a3.z) * inv,
                                        (a0.w + a1.w + a2.w + a3.w) * inv);
    }
    __syncthreads();

    float acc[RF];
    #pragma unroll
    for (int r = 0; r < RF; r++) acc[r] = bo[t];
    for (int d4 = 0; d4 < DM / 4; d4++) {
        float w0 = Wo[(4 * d4 + 0) * DM + t];
        float w1 = Wo[(4 * d4 + 1) * DM + t];
        float w2 = Wo[(4 * d4 + 2) * DM + t];
        float w3 = Wo[(4 * d4 + 3) * DM + t];
        #pragma unroll
        for (int r = 0; r < RF; r++) {
            float4 av = ((const float4*)&a_s[r * DM])[d4];
            acc[r] += av.x * w0 + av.y * w1 + av.z * w2 + av.w * w3;
        }
    }
    #pragma unroll
    for (int r = 0; r < RF; r++) x[(row0 + r) * DM + t] += acc[r];
}

// fused tail: LN2 -> FFN -> +x -> LNf -> relu@Wtout -> @Watt/relu -> hp.
__global__ void k_ffn_fused(const float* __restrict__ x,
                            const float* __restrict__ ln2_g, const float* __restrict__ ln2_b,
                            const float* __restrict__ W1, const float* __restrict__ b1,
                            const float* __restrict__ W2, const float* __restrict__ b2,
                            const float* __restrict__ lnf_g, const float* __restrict__ lnf_b,
                            const float* __restrict__ Wtout, const float* __restrict__ btout,
                            const float* __restrict__ Watt, const float* __restrict__ batt,
                            float* __restrict__ hp) {
    long row0 = (long)blockIdx.x * RF;
    int t = threadIdx.x;  // 512

    __shared__ float x_s[RF][DM];       // 8 KB
    __shared__ float xn_s[RF][DM];      // 8 KB
    __shared__ float h_s[RF][DFF];      // 32 KB
    __shared__ float r_s[RF][DM + 4];   // 8.25 KB
    __shared__ float wt_s[DM * DIM];    // 5 KB
    __shared__ float wa_s[DIM * DIM];
    __shared__ float bt_s[DIM], ba_s[DIM];
    __shared__ float wv_s[RF][DIM];

    {
        float4 xv = ((const float4*)(x + row0 * DM))[t];
        ((float4*)&x_s[0][0])[t] = xv;
        for (int i = t; i < DM * DIM; i += 512) wt_s[i] = Wtout[i];
        for (int i = t; i < DIM * DIM; i += 512) wa_s[i] = Watt[i];
        if (t < DIM) { bt_s[t] = btout[t]; ba_s[t] = batt[t]; }
    }
    __syncthreads();

    {
        int row = t >> 5, c = t & 31;
        float4 v = ((const float4*)&x_s[row][0])[c];
        float s = half_reduce_sum(v.x + v.y + v.z + v.w);
        float mean = s / (float)DM;
        float4 dv = make_float4(v.x - mean, v.y - mean, v.z - mean, v.w - mean);
        float q = half_reduce_sum(dv.x * dv.x + dv.y * dv.y + dv.z * dv.z + dv.w * dv.w);
        float sd = sqrtf(q / (float)(DM - 1)) + 1e-6f;
        const float4 g4 = ((const float4*)ln2_g)[c];
        const float4 b4 = ((const float4*)ln2_b)[c];
        ((float4*)&xn_s[row][0])[c] = make_float4(
            g4.x * dv.x / sd + b4.x, g4.y * dv.y / sd + b4.y,
            g4.z * dv.z / sd + b4.z, g4.w * dv.w / sd + b4.w);
    }
    __syncthreads();

    {
        float acc[RF];
        #pragma unroll
        for (int r = 0; r < RF; r++) acc[r] = b1[t];
        for (int d4 = 0; d4 < DM / 4; d4++) {
            float w0 = W1[(4 * d4 + 0) * DFF + t];
            float w1 = W1[(4 * d4 + 1) * DFF + t];
            float w2 = W1[(4 * d4 + 2) * DFF + t];
            float w3 = W1[(4 * d4 + 3) * DFF + t];
            #pragma unroll
            for (int r = 0; r < RF; r++) {
                float4 xv = ((const float4*)&xn_s[r][0])[d4];
                acc[r] += xv.x * w0 + xv.y * w1 + xv.z * w2 + xv.w * w3;
            }
        }
        #pragma unroll
        for (int r = 0; r < RF; r++) h_s[r][t] = fmaxf(acc[r], 0.f);
    }
    __syncthreads();

    {
        int col = t & 127, rq = t >> 7;
        float acc2[4];
        #pragma unroll
        for (int rr = 0; rr < 4; rr++) acc2[rr] = b2[col];
        for (int f4 = 0; f4 < DFF / 4; f4++) {
            float w0 = W2[(4 * f4 + 0) * DM + col];
            float w1 = W2[(4 * f4 + 1) * DM + col];
            float w2 = W2[(4 * f4 + 2) * DM + col];
            float w3 = W2[(4 * f4 + 3) * DM + col];
            #pragma unroll
            for (int rr = 0; rr < 4; rr++) {
                float4 hv = ((const float4*)&h_s[rq * 4 + rr][0])[f4];
                acc2[rr] += hv.x * w0 + hv.y * w1 + hv.z * w2 + hv.w * w3;
            }
        }
        __syncthreads();
        #pragma unroll
        for (int rr = 0; rr < 4; rr++) {
            int row = rq * 4 + rr;
            xn_s[row][col] = x_s[row][col] + acc2[rr];
        }
    }
    __syncthreads();

    {
        int row = t >> 5, c = t & 31;
        float4 v = ((const float4*)&xn_s[row][0])[c];
        float s = half_reduce_sum(v.x + v.y + v.z + v.w);
        float mean = s / (float)DM;
        float4 dv = make_float4(v.x - mean, v.y - mean, v.z - mean, v.w - mean);
        float q = half_reduce_sum(dv.x * dv.x + dv.y * dv.y + dv.z * dv.z + dv.w * dv.w);
        float sd = sqrtf(q / (float)(DM - 1)) + 1e-6f;
        const float4 g4 = ((const float4*)lnf_g)[c];
        const float4 b4 = ((const float4*)lnf_b)[c];
        r_s[row][4 * c + 0] = fmaxf(g4.x * dv.x / sd + b4.x, 0.f);
        r_s[row][4 * c + 1] = fmaxf(g4.y * dv.y / sd + b4.y, 0.f);
        r_s[row][4 * c + 2] = fmaxf(g4.z * dv.z / sd + b4.z, 0.f);
        r_s[row][4 * c + 3] = fmaxf(g4.w * dv.w / sd + b4.w, 0.f);
    }
    __syncthreads();

    if (t < RF * DIM) {
        int row = t / DIM, o = t % DIM;
        float acc = bt_s[o];
        for (int d = 0; d < DM; d++) acc += r_s[row][d] * wt_s[d * DIM + o];
        wv_s[row][o] = acc;
    }
    __syncthreads();

    if (t < RF * DIM) {
        int row = t / DIM, o = t % DIM;
        float acc = ba_s[o];
        #pragma unroll
        for (int e = 0; e < DIM; e++) acc += wv_s[row][e] * wa_s[e * DIM + o];
        hp[(row0 + row) * DIM + o] = fmaxf(acc, 0.f);
    }
}

// final: hc = relu(compound@Watt+batt); w = tanh(hc.hp); protein mean; MLP; out.
__global__ void k_final(const float* __restrict__ hp, const float* __restrict__ compound,
                        const float* __restrict__ Watt, const float* __restrict__ batt,
                        const float* __restrict__ Wout, const float* __restrict__ bout,
                        const float* __restrict__ Wint, const float* __restrict__ bint,
                        float* __restrict__ out) {
    int b = blockIdx.x;
    int t = threadIdx.x;  // 256
    int wid = t >> 6, lane = t & 63;

    __shared__ float wout_s[LO * 2 * DIM * 2 * DIM];
    __shared__ float bout_s[LO * 2 * DIM];
    __shared__ float wint_s[2 * DIM * 2];
    __shared__ float bint_s[2];
    __shared__ float comp_s[DIM];
    __shared__ float hc_s[DIM];
    __shared__ float red[4][DIM];
    __shared__ float cat_s[2 * DIM];
    __shared__ float tmp_s[2 * DIM];

    for (int i = t; i < LO * 2 * DIM * 2 * DIM; i += 256) wout_s[i] = Wout[i];
    for (int i = t; i < LO * 2 * DIM; i += 256) bout_s[i] = bout[i];
    for (int i = t; i < 2 * DIM * 2; i += 256) wint_s[i] = Wint[i];
    if (t < 2) bint_s[t] = bint[t];
    if (t < DIM) comp_s[t] = compound[b * DIM + t];
    __syncthreads();
    if (t < DIM) {
        float acc = batt[t];
        #pragma unroll
        for (int e = 0; e < DIM; e++) acc += comp_s[e] * Watt[e * DIM + t];
        hc_s[t] = fmaxf(acc, 0.f);
    }
    __syncthreads();

    float lacc[DIM];
    #pragma unroll
    for (int e = 0; e < DIM; e++) lacc[e] = 0.f;
    for (int l = t; l < L; l += 256) {
        const float* hpl = hp + ((long)b * L + l) * DIM;
        float hv[DIM];
        float dot = 0.f;
        #pragma unroll
        for (int e = 0; e < DIM; e++) { hv[e] = hpl[e]; dot += hc_s[e] * hv[e]; }
        float w = tanhf(dot);
        #pragma unroll
        for (int e = 0; e < DIM; e++) lacc[e] += w * hv[e];
    }
    #pragma unroll
    for (int e = 0; e < DIM; e++) lacc[e] = wave_reduce_sum(lacc[e]);
    if (lane == 0) {
        #pragma unroll
        for (int e = 0; e < DIM; e++) red[wid][e] = lacc[e];
    }
    __syncthreads();
    if (t < DIM) {
        cat_s[t] = comp_s[t];
        cat_s[DIM + t] = (red[0][t] + red[1][t] + red[2][t] + red[3][t]) / (float)L;
    }
    __syncthreads();

    for (int j = 0; j < LO; j++) {
        float acc = 0.f;
        if (t < 2 * DIM) {
            acc = bout_s[j * 2 * DIM + t];
            #pragma unroll
            for (int e = 0; e < 2 * DIM; e++)
                acc += cat_s[e] * wout_s[j * 2 * DIM * 2 * DIM + e * 2 * DIM + t];
            acc = fmaxf(acc, 0.f);
            tmp_s[t] = acc;
        }
        __syncthreads();
        if (t < 2 * DIM) cat_s[t] = tmp_s[t];
        __syncthreads();
    }
    if (t < 2) {
        float o = bint_s[t];
        #pragma unroll
        for (int e = 0; e < 2 * DIM; e++) o += cat_s[e] * wint_s[e * 2 + t];
        out[b * 2 + t] = o;
    }
}

extern "C" void kernel_launch(void* const* d_in, const int* in_sizes, int n_in,
                              void* d_out, int out_size, void* d_ws, size_t ws_size,
                              hipStream_t stream) {
    (void)in_sizes; (void)n_in; (void)out_size; (void)ws_size;
    const int*   fingerprints = (const int*)d_in[0];
    const float* fp_mask      = (const float*)d_in[1];
    const int*   adjacency    = (const int*)d_in[2];
    const int*   words        = (const int*)d_in[3];
    const float* words_mask   = (const float*)d_in[4];
    const float* emb_fp       = (const float*)d_in[5];
    const float* emb_word     = (const float*)d_in[6];
    const float* Wg   = (const float*)d_in[7];
    const float* bg   = (const float*)d_in[8];
    const float* attn_a = (const float*)d_in[9];
    const float* Wq = (const float*)d_in[10];
    const float* bq = (const float*)d_in[11];
    const float* Wk = (const float*)d_in[12];
    const float* bk = (const float*)d_in[13];
    const float* Wv = (const float*)d_in[14];
    const float* bv = (const float*)d_in[15];
    const float* Wo = (const float*)d_in[16];
    const float* bo = (const float*)d_in[17];
    const float* ln1_g = (const float*)d_in[18];
    const float* ln1_b = (const float*)d_in[19];
    const float* ln2_g = (const float*)d_in[20];
    const float* ln2_b = (const float*)d_in[21];
    const float* lnf_g = (const float*)d_in[22];
    const float* lnf_b = (const float*)d_in[23];
    const float* W1 = (const float*)d_in[24];
    const float* b1 = (const float*)d_in[25];
    const float* W2 = (const float*)d_in[26];
    const float* b2 = (const float*)d_in[27];
    const float* Wtout = (const float*)d_in[28];
    const float* btout = (const float*)d_in[29];
    const float* Watt  = (const float*)d_in[30];
    const float* batt  = (const float*)d_in[31];
    const float* Wout  = (const float*)d_in[32];
    const float* bout  = (const float*)d_in[33];
    const float* Wint  = (const float*)d_in[34];
    const float* bint  = (const float*)d_in[35];
    float* out = (float*)d_out;

    float* w = (float*)d_ws;
    float* xs = w;        w += B * N * DIM;
    float* h  = w;        w += B * N * DIM;
    float* s1 = w;        w += B * N;
    float* s2 = w;        w += B * N;
    float* compound = w;  w += B * DIM;
    float* x  = w;        w += (long)B * L * DM;
    float* qb = w;        w += (long)B * H * L * DK;
    float* kb = w;        w += (long)B * H * L * DK;
    float* vb = w;        w += (long)B * H * L * DK;
    float* attn_p = w;    w += (long)NSEG * B * L * DM;
    float* ssum_p = w;    w += (long)NSEG * B * H * L;
    float* hp = w;        w += (long)B * L * DIM;

    // ---- GNN ----
    for (int i = 0; i < LG; i++) {
        k_gnn_h<<<(B * N + 255) / 256, 256, 0, stream>>>(
            fingerprints, emb_fp, xs, fp_mask,
            Wg + i * DIM * DIM, bg + i * DIM, attn_a + i * 2 * DIM, h, s1, s2, i == 0);
        k_gnn_att<<<B * (N / 16), 256, 0, stream>>>(h, s1, s2, adjacency, xs);
    }
    k_compound<<<B, 256, 0, stream>>>(xs, fp_mask, compound);

    // ---- Transformer ----
    k_qkv<<<B * L / RF, 3 * DM, 0, stream>>>(words, emb_word, ln1_g, ln1_b,
                                             Wq, bq, Wk, bk, Wv, bv, x, qb, kb, vb);
    k_attn<<<B * H * (L / AQR2) * NSEG, 256, 0, stream>>>(qb, kb, vb, words_mask, attn_p, ssum_p);
    k_oproj<<<B * L / RF, DM, 0, stream>>>(attn_p, ssum_p, Wo, bo, x);
    k_ffn_fused<<<B * L / RF, DFF, 0, stream>>>(x, ln2_g, ln2_b, W1, b1, W2, b2,
                                                lnf_g, lnf_b, Wtout, btout, Watt, batt, hp);
    k_final<<<B, 256, 0, stream>>>(hp, compound, Watt, batt,
                                   Wout, bout, Wint, bint, out);
}